// Round 18
// baseline (86.863 us; speedup 1.0000x reference)
//
#include <hip/hip_runtime.h>
#include <hip/hip_bf16.h>

typedef __attribute__((ext_vector_type(8))) short bf16x8;
typedef __attribute__((ext_vector_type(4))) float f32x4;

#define B_N 4096
#define DIM 512
#define HBINS 8192

// workspace byte offsets
#define OFF_PARAMS 0                 // 256 B
#define OFF_X2     256
#define OFF_Y2     16640
#define OFF_YSY    33024             // stats contiguous: [256, 49408)
#define OFF_HIST   49408             // 32 KB; [49408, 82176)
#define OFF_TILES  98304             // 4KB aligned
#define MAT_ELEMS  2097152           // 4096*512 bf16 elems per matrix (4 MB)
#define WS_NEED    (OFF_TILES + (size_t)4 * MAT_ELEMS * 2)

static __device__ __forceinline__ unsigned short f2bf_rne(float f) {
    unsigned int u = __float_as_uint(f);
    u += 0x7FFFu + ((u >> 16) & 1u);
    return (unsigned short)(u >> 16);
}
static __device__ __forceinline__ float bf2f(unsigned short h) {
    return __uint_as_float(((unsigned int)h) << 16);
}

// swizzled tile index (hist staging + fallback path)
static __device__ __forceinline__ int swz(int r, int k) {
    return r * 32 + ((((k >> 3) ^ ((r >> 1) & 3))) << 3) + (k & 7);
}

// median selection from an LDS-resident histogram (256 threads). Returns via vv[2].
static __device__ __forceinline__ void median_from_lds(
    unsigned int* hsum, unsigned int* part, float* vv, int t) {
    unsigned int s = 0;
#pragma unroll 8
    for (int b = t * 32; b < t * 32 + 32; ++b) s += hsum[b];
    part[t] = s;
    __syncthreads();
    unsigned int pre = 0;
    for (int i = 0; i < 256; ++i) {
        unsigned int v = part[i];
        if (i < t) pre += v;
    }
    const unsigned int kk1 = 131072u, kk2 = 131073u;
    unsigned int hi = pre + s;
#pragma unroll
    for (int sel = 0; sel < 2; ++sel) {
        unsigned int kk = sel ? kk2 : kk1;
        if (kk > pre && kk <= hi) {      // exactly one owner thread
            unsigned int cc = pre;
            for (int b = 0; b < 32; ++b) {
                cc += hsum[t * 32 + b];
                if (cc >= kk) { vv[sel] = ((float)(t * 32 + b) + 0.5f) * 0.25f; break; }
            }
        }
    }
    __syncthreads();
}

// FRAG-MAJOR tile layout (main path, all 4 matrices):
//   elem (row, k) of a 128x32 tile -> (row>>4)*512 + (((k>>3)&3)*16 + (row&15))*8 + (k&7)

// ---------------- K_preAll: fused conversion (c1-independent) + sample hist ----------------
__global__ __launch_bounds__(256) void k_preAll(
    const float* __restrict__ X, const float* __restrict__ Y,
    const float* __restrict__ SY, unsigned short* __restrict__ tiles,
    float* __restrict__ x2, float* __restrict__ y2, float* __restrict__ ysy,
    unsigned int* __restrict__ hist) {
    __shared__ __align__(16) unsigned short sAB[4096];   // hist: sA=[0,2048), sB=[2048,4096)
    __shared__ unsigned int hloc[HBINS];
    __shared__ float rn[128];

    int b = blockIdx.x, t = threadIdx.x;

    if (b < 512) {
        // -------- conversion --------
        int side = b >> 8;                 // 0: X, 1: Y/SY
        int tile = (b & 255) >> 3;
        int ky = b & 7;
        unsigned short* base0 = tiles + (size_t)side * 2 * MAT_ELEMS;
        unsigned short* base1 = base0 + MAT_ELEMS;       // side1 only (SY)
#pragma unroll
        for (int kt2 = 0; kt2 < 2; ++kt2) {
            int kt = ky * 2 + kt2;
            unsigned short* d0 = base0 + (size_t)(tile * 16 + kt) * 4096;
            unsigned short* d1 = base1 + (size_t)(tile * 16 + kt) * 4096;
#pragma unroll
            for (int c = 0; c < 2; ++c) {
                int v = c * 256 + t;
                int r = (v >> 6) * 16 + (v & 15);
                int k = ((v >> 4) & 3) << 3;
                const float* gp = (side ? Y : X) + (size_t)(tile * 128 + r) * DIM + kt * 32 + k;
                float4 p0 = *(const float4*)gp;
                float4 p1 = *(const float4*)(gp + 4);
                float pv[8] = {p0.x, p0.y, p0.z, p0.w, p1.x, p1.y, p1.z, p1.w};
                float s1 = 0.f, s2 = 0.f;
                bf16x8 h0;
                if (side) {
                    const float* gq = SY + (size_t)(tile * 128 + r) * DIM + kt * 32 + k;
                    float4 q0 = *(const float4*)gq;
                    float4 q1 = *(const float4*)(gq + 4);
                    float qv[8] = {q0.x, q0.y, q0.z, q0.w, q1.x, q1.y, q1.z, q1.w};
                    bf16x8 h1;
#pragma unroll
                    for (int j = 0; j < 8; ++j) {
                        s1 += pv[j] * pv[j];
                        s2 += pv[j] * qv[j];
                        h0[j] = (short)f2bf_rne(pv[j]);
                        h1[j] = (short)f2bf_rne(qv[j]);
                    }
                    *(bf16x8*)&d1[v * 8] = h1;
                } else {
#pragma unroll
                    for (int j = 0; j < 8; ++j) {
                        s1 += pv[j] * pv[j];
                        h0[j] = (short)f2bf_rne(pv[j]);
                    }
                }
                *(bf16x8*)&d0[v * 8] = h0;
                s1 += __shfl_xor(s1, 16); s1 += __shfl_xor(s1, 32);
                if (side) { s2 += __shfl_xor(s2, 16); s2 += __shfl_xor(s2, 32); }
                if ((t & 48) == 0) {
                    int row = tile * 128 + r;
                    if (side == 0) {
                        atomicAdd(&x2[row], s1);
                    } else {
                        atomicAdd(&y2[row], s1);
                        atomicAdd(&ysy[row], s2);
                    }
                }
            }
        }
    } else {
        // -------- sample histogram (64x64 tile, full K) --------
        unsigned short* sA = &sAB[0];
        unsigned short* sB = &sAB[2048];
        float* x2s = &rn[0];
        float* y2s = &rn[64];
        int hb = b - 512;
        int bi = hb >> 3, bj = hb & 7;
        for (int i = t; i < HBINS; i += 256) hloc[i] = 0;

        int lane = t & 63, w = t >> 6;
        int wm = w >> 1, wn = w & 1;
        int fr = lane & 15, fko = (lane >> 4) * 8;

        f32x4 axy[2][2];
#pragma unroll
        for (int i = 0; i < 2; ++i)
#pragma unroll
            for (int j = 0; j < 2; ++j) axy[i][j] = (f32x4)0.f;

        int r = t >> 2, k0 = (t & 3) * 8;
        const float* gx = X + (size_t)(bi * 64 + r) * DIM + k0;
        const float* gy = Y + (size_t)(bj * 64 + r) * DIM + k0;

        int ixA[2], ixB[2];
#pragma unroll
        for (int fm = 0; fm < 2; ++fm) ixA[fm] = swz(wm * 32 + fm * 16 + fr, fko);
#pragma unroll
        for (int fn = 0; fn < 2; ++fn) ixB[fn] = swz(wn * 32 + fn * 16 + fr, fko);

        float na = 0.f, nb = 0.f;
        float4 A0, A1, B0, B1;
#define LDK(kt_) do {                                                       \
            A0 = *(const float4*)(gx + (kt_) * 32);                         \
            A1 = *(const float4*)(gx + (kt_) * 32 + 4);                     \
            B0 = *(const float4*)(gy + (kt_) * 32);                         \
            B1 = *(const float4*)(gy + (kt_) * 32 + 4);                     \
        } while (0)

        LDK(0);
        for (int kt = 0; kt < 16; ++kt) {
            float av[8] = {A0.x, A0.y, A0.z, A0.w, A1.x, A1.y, A1.z, A1.w};
            float bv[8] = {B0.x, B0.y, B0.z, B0.w, B1.x, B1.y, B1.z, B1.w};
            bf16x8 ha, hb2;
#pragma unroll
            for (int j = 0; j < 8; ++j) {
                na += av[j] * av[j];
                nb += bv[j] * bv[j];
                ha[j] = (short)f2bf_rne(av[j]);
                hb2[j] = (short)f2bf_rne(bv[j]);
            }
            __syncthreads();
            *(bf16x8*)&sA[swz(r, k0)] = ha;
            *(bf16x8*)&sB[swz(r, k0)] = hb2;
            if (kt < 15) LDK(kt + 1);
            __syncthreads();

            bf16x8 aX[2];
#pragma unroll
            for (int fm = 0; fm < 2; ++fm) aX[fm] = *(const bf16x8*)&sA[ixA[fm]];
#pragma unroll
            for (int fn = 0; fn < 2; ++fn) {
                bf16x8 bY = *(const bf16x8*)&sB[ixB[fn]];
#pragma unroll
                for (int fm = 0; fm < 2; ++fm)
                    axy[fm][fn] = __builtin_amdgcn_mfma_f32_16x16x32_bf16(aX[fm], bY, axy[fm][fn], 0, 0, 0);
            }
        }
#undef LDK

        na += __shfl_xor(na, 1); na += __shfl_xor(na, 2);
        nb += __shfl_xor(nb, 1); nb += __shfl_xor(nb, 2);
        if ((t & 3) == 0) { x2s[r] = na; y2s[r] = nb; }
        __syncthreads();

        int fq = lane >> 4;
#pragma unroll
        for (int fm = 0; fm < 2; ++fm)
#pragma unroll
            for (int fn = 0; fn < 2; ++fn)
#pragma unroll
                for (int rr = 0; rr < 4; ++rr) {
                    int rl = wm * 32 + fm * 16 + fq * 4 + rr;
                    int cl = wn * 32 + fn * 16 + fr;
                    float d = fmaxf(x2s[rl] + y2s[cl] - 2.0f * axy[fm][fn][rr], 0.0f);
                    int bin = (int)(d * 4.0f);
                    if (bin > HBINS - 1) bin = HBINS - 1;
                    atomicAdd(&hloc[bin], 1u);
                }
        __syncthreads();
        for (int i = t; i < HBINS; i += 256) {
            unsigned int v = hloc[i];
            if (v) atomicAdd(&hist[i], v);
        }
    }
}

// ---------------- K_preC: per-block median + mat1 = bf16(SX + c1*X) ----------------
__global__ __launch_bounds__(256) void k_preC(
    const float* __restrict__ X, const float* __restrict__ SX,
    const unsigned int* __restrict__ hist, float* __restrict__ params,
    unsigned short* __restrict__ tiles) {
    __shared__ unsigned int hsum[HBINS];
    __shared__ unsigned int part[256];
    __shared__ float vv[2];
    int t = threadIdx.x;
    for (int i = t; i < HBINS / 4; i += 256)
        ((uint4*)hsum)[i] = ((const uint4*)hist)[i];
    __syncthreads();
    median_from_lds(hsum, part, vv, t);
    float med = 0.5f * (vv[0] + vv[1]);
    float bw = fminf(fmaxf(sqrtf(med * 0.5f), 0.1f), 10.0f);
    float h2 = bw * bw;
    float c1 = 1.0f / h2;
    if (blockIdx.x == 0 && blockIdx.y == 0 && t == 0) {
        params[0] = 1.0f / (2.0f * h2);
        params[1] = c1;
        params[2] = 1.0f / (h2 * h2);
        params[3] = (float)DIM / h2;
    }

    int tile = blockIdx.x;
    unsigned short* base1 = tiles + MAT_ELEMS;
#pragma unroll
    for (int kt2 = 0; kt2 < 2; ++kt2) {
        int kt = blockIdx.y * 2 + kt2;
        unsigned short* d1 = base1 + (size_t)(tile * 16 + kt) * 4096;
#pragma unroll
        for (int c = 0; c < 2; ++c) {
            int v = c * 256 + t;
            int r = (v >> 6) * 16 + (v & 15);
            int k = ((v >> 4) & 3) << 3;
            const float* gp = X + (size_t)(tile * 128 + r) * DIM + kt * 32 + k;
            const float* gq = SX + (size_t)(tile * 128 + r) * DIM + kt * 32 + k;
            float4 p0 = *(const float4*)gp;
            float4 p1 = *(const float4*)(gp + 4);
            float4 q0 = *(const float4*)gq;
            float4 q1 = *(const float4*)(gq + 4);
            float pv[8] = {p0.x, p0.y, p0.z, p0.w, p1.x, p1.y, p1.z, p1.w};
            float qv[8] = {q0.x, q0.y, q0.z, q0.w, q1.x, q1.y, q1.z, q1.w};
            bf16x8 h1;
#pragma unroll
            for (int j = 0; j < 8; ++j) h1[j] = (short)f2bf_rne(qv[j] + c1 * pv[j]);
            *(bf16x8*)&d1[v * 8] = h1;
        }
    }
}

// ---------------- K_main: 128x64 block tile, 4 waves of 64x32, higher occupancy ----------------
// acc = 64 VGPR/wave (vs 128 at 128x128) -> ~3 waves/SIMD; LDS 25 KB -> 3+ blocks/CU.
#define GLD(g, l) __builtin_amdgcn_global_load_lds(                                   \
    (const __attribute__((address_space(1))) void*)(g),                               \
    (__attribute__((address_space(3))) void*)(l), 16, 0, 0)

__global__ __launch_bounds__(256, 3) void k_main(
    const unsigned short* __restrict__ tiles,
    const float* __restrict__ x2g, const float* __restrict__ y2g,
    const float* __restrict__ ysyg, const float* __restrict__ params,
    float* __restrict__ out) {
    __shared__ __align__(16) unsigned short sA[2][4096];  // X tile 128x32, frag-major
    __shared__ __align__(16) unsigned short sB[2][2048];  // Y half-tile 64x32
    __shared__ float x2s[128], y2s[64], ysys[64];

    int t = threadIdx.x;
    int bm = blockIdx.y, bn = blockIdx.x;   // bm in [0,32): 128 rows; bn in [0,64): 64 cols
    if (t < 128) x2s[t] = x2g[bm * 128 + t];
    else if (t < 192) y2s[t - 128] = y2g[bn * 64 + (t - 128)];
    else ysys[t - 192] = ysyg[bn * 64 + (t - 192)];
    __syncthreads();

    int lane = t & 63, w = t >> 6;
    int wm = w >> 1, wn = w & 1;       // wave tile 64x32 at (wm*64, wn*32)

    f32x4 axy[4][2], acb[4][2];
#pragma unroll
    for (int i = 0; i < 4; ++i)
#pragma unroll
        for (int j = 0; j < 2; ++j) { axy[i][j] = (f32x4)0.f; acb[i][j] = (f32x4)0.f; }

    int tileB = bn >> 1, half = bn & 1;     // 64-row half of the stored 128-row tile
    const unsigned short* gaX = tiles + (size_t)(bm * 16) * 4096 + t * 8;
    const unsigned short* gbY = tiles + (size_t)2 * MAT_ELEMS + (size_t)(tileB * 16) * 4096
                              + half * 2048 + t * 8;
    const unsigned short* gaC = tiles + (size_t)MAT_ELEMS + (size_t)(bm * 16) * 4096
                              + (wm * 4) * 512 + lane * 8;
    const unsigned short* gbS = tiles + (size_t)3 * MAT_ELEMS + (size_t)(tileB * 16) * 4096
                              + half * 2048 + (wn * 2) * 512 + lane * 8;

#define STAGE(buf, kt_) do {                                                     \
        const unsigned short* pa_ = gaX + (size_t)(kt_) * 4096;                  \
        const unsigned short* pb_ = gbY + (size_t)(kt_) * 4096;                  \
        GLD(pa_,        &sA[buf][t * 8]);                                        \
        GLD(pa_ + 2048, &sA[buf][2048 + t * 8]);                                 \
        GLD(pb_,        &sB[buf][t * 8]);                                        \
    } while (0)

#define FRAGLD(dC, dS, kt_) do {                                                 \
        const unsigned short* pc_ = gaC + (size_t)(kt_) * 4096;                  \
        const unsigned short* ps_ = gbS + (size_t)(kt_) * 4096;                  \
        dC[0] = *(const bf16x8*)(pc_);                                           \
        dC[1] = *(const bf16x8*)(pc_ + 512);                                     \
        dC[2] = *(const bf16x8*)(pc_ + 1024);                                    \
        dC[3] = *(const bf16x8*)(pc_ + 1536);                                    \
        dS[0] = *(const bf16x8*)(ps_);                                           \
        dS[1] = *(const bf16x8*)(ps_ + 512);                                     \
    } while (0)

    int ixA[4], ixB[2];
#pragma unroll
    for (int fm = 0; fm < 4; ++fm) ixA[fm] = (wm * 4 + fm) * 512 + lane * 8;
#pragma unroll
    for (int fn = 0; fn < 2; ++fn) ixB[fn] = (wn * 2 + fn) * 512 + lane * 8;

    bf16x8 fC0[4], fS0[2], fC1[4], fS1[2];

// r13-style dbuf K-step. FIFO: top vmcnt(6) completes STAGE(CB)'s 3 loads,
// leaving the 6 FRAG loads in flight (compiler waits them before MFMA use).
#define KSTEP(CB, CURC, CURS, NXTC, NXTS, NKT, DOPF) do {                        \
        asm volatile("s_waitcnt vmcnt(6)" ::: "memory");   /* staging of CB done */\
        __builtin_amdgcn_sched_barrier(0);                                       \
        __builtin_amdgcn_s_barrier();                                            \
        __builtin_amdgcn_sched_barrier(0);                                       \
        if (DOPF) {                                                              \
            STAGE(CB ^ 1, NKT);                                                  \
            FRAGLD(NXTC, NXTS, NKT);                                             \
        }                                                                        \
        bf16x8 dX[4], dY[2];                                                     \
        dX[0] = *(const bf16x8*)&sA[CB][ixA[0]];                                 \
        dX[1] = *(const bf16x8*)&sA[CB][ixA[1]];                                 \
        dX[2] = *(const bf16x8*)&sA[CB][ixA[2]];                                 \
        dX[3] = *(const bf16x8*)&sA[CB][ixA[3]];                                 \
        dY[0] = *(const bf16x8*)&sB[CB][ixB[0]];                                 \
        dY[1] = *(const bf16x8*)&sB[CB][ixB[1]];                                 \
        __builtin_amdgcn_s_setprio(1);                                           \
        _Pragma("unroll")                                                        \
        for (int fn_ = 0; fn_ < 2; ++fn_) {                                      \
            _Pragma("unroll")                                                    \
            for (int fm_ = 0; fm_ < 4; ++fm_) {                                  \
                axy[fm_][fn_] = __builtin_amdgcn_mfma_f32_16x16x32_bf16(         \
                    dX[fm_], dY[fn_], axy[fm_][fn_], 0, 0, 0);                   \
                acb[fm_][fn_] = __builtin_amdgcn_mfma_f32_16x16x32_bf16(         \
                    CURC[fm_], CURS[fn_], acb[fm_][fn_], 0, 0, 0);               \
            }                                                                    \
        }                                                                        \
        __builtin_amdgcn_s_setprio(0);                                           \
        __builtin_amdgcn_sched_barrier(0);                                       \
    } while (0)

    STAGE(0, 0);
    FRAGLD(fC0, fS0, 0);

    for (int k2 = 0; k2 < 7; ++k2) {
        KSTEP(0, fC0, fS0, fC1, fS1, 2 * k2 + 1, 1);
        KSTEP(1, fC1, fS1, fC0, fS0, 2 * k2 + 2, 1);
    }
    KSTEP(0, fC0, fS0, fC1, fS1, 15, 1);
    KSTEP(1, fC1, fS1, fC0, fS0, 0, 0);
#undef KSTEP
#undef STAGE
#undef FRAGLD

    float c0 = params[0], c1 = params[1], c2 = params[2], c3 = params[3];
    int fr = lane & 15, fq = lane >> 4;
#pragma unroll
    for (int fm = 0; fm < 4; ++fm) {
#pragma unroll
        for (int fn = 0; fn < 2; ++fn) {
#pragma unroll
            for (int r = 0; r < 4; ++r) {
                int rl = wm * 64 + fm * 16 + fq * 4 + r;
                int cl = wn * 32 + fn * 16 + fr;
                float d = fmaxf(x2s[rl] + y2s[cl] - 2.0f * axy[fm][fn][r], 0.0f);
                float kv = __expf(-d * c0);
                out[(size_t)(bm * 128 + rl) * B_N + (bn * 64 + cl)] =
                    kv * (acb[fm][fn][r] - c1 * ysys[cl] + d * c2 - c3);
            }
        }
    }
}

// ---------------- Fallback path (small ws) ----------------
__global__ void k_rowstats(const float* __restrict__ X, const float* __restrict__ Y,
                           const float* __restrict__ SY,
                           float* __restrict__ x2, float* __restrict__ y2,
                           float* __restrict__ ysy) {
    int t = threadIdx.x;
    int r = blockIdx.x * 4 + (t >> 6);
    int lane = t & 63;
    const float4* px = (const float4*)(X + (size_t)r * DIM) + lane * 2;
    const float4* py = (const float4*)(Y + (size_t)r * DIM) + lane * 2;
    const float4* ps = (const float4*)(SY + (size_t)r * DIM) + lane * 2;
    float4 a0 = px[0], a1 = px[1];
    float4 b0 = py[0], b1 = py[1];
    float4 c0 = ps[0], c1 = ps[1];
    float s1 = a0.x*a0.x + a0.y*a0.y + a0.z*a0.z + a0.w*a0.w
             + a1.x*a1.x + a1.y*a1.y + a1.z*a1.z + a1.w*a1.w;
    float s2 = b0.x*b0.x + b0.y*b0.y + b0.z*b0.z + b0.w*b0.w
             + b1.x*b1.x + b1.y*b1.y + b1.z*b1.z + b1.w*b1.w;
    float s3 = b0.x*c0.x + b0.y*c0.y + b0.z*c0.z + b0.w*c0.w
             + b1.x*c1.x + b1.y*c1.y + b1.z*c1.z + b1.w*c1.w;
#pragma unroll
    for (int o = 32; o > 0; o >>= 1) {
        s1 += __shfl_down(s1, o);
        s2 += __shfl_down(s2, o);
        s3 += __shfl_down(s3, o);
    }
    if (lane == 0) { x2[r] = s1; y2[r] = s2; ysy[r] = s3; }
}

__global__ void k_hist_fp32(const float* __restrict__ X, const float* __restrict__ Y,
                            const float* __restrict__ x2, const float* __restrict__ y2,
                            unsigned int* __restrict__ hist) {
    __shared__ float xs[32][68];
    __shared__ float ys[32][68];
    __shared__ unsigned int hloc[HBINS];
    int t = threadIdx.x;
    for (int i = t; i < HBINS; i += 256) hloc[i] = 0;
    int i0 = blockIdx.y * 32, j0 = blockIdx.x * 32;
    float a00 = 0.f, a01 = 0.f, a10 = 0.f, a11 = 0.f;
    int ti = (t >> 4) * 2, tj = (t & 15) * 2;
    for (int c = 0; c < 8; ++c) {
        __syncthreads();
        int rr = t >> 3, cc = (t & 7) * 8;
        const float* gx = X + (size_t)(i0 + rr) * DIM + c * 64 + cc;
        *(float4*)&xs[rr][cc] = *(const float4*)gx;
        *(float4*)&xs[rr][cc + 4] = *(const float4*)(gx + 4);
        const float* gy = Y + (size_t)(j0 + rr) * DIM + c * 64 + cc;
        *(float4*)&ys[rr][cc] = *(const float4*)gy;
        *(float4*)&ys[rr][cc + 4] = *(const float4*)(gy + 4);
        __syncthreads();
        for (int kk = 0; kk < 64; ++kk) {
            float a0 = xs[ti][kk], a1 = xs[ti + 1][kk];
            float b0 = ys[tj][kk], b1 = ys[tj + 1][kk];
            a00 += a0 * b0; a01 += a0 * b1; a10 += a1 * b0; a11 += a1 * b1;
        }
    }
    float s[2][2] = {{a00, a01}, {a10, a11}};
#pragma unroll
    for (int ii = 0; ii < 2; ++ii)
#pragma unroll
        for (int jj = 0; jj < 2; ++jj) {
            float d = fmaxf(x2[i0 + ti + ii] + y2[j0 + tj + jj] - 2.f * s[ii][jj], 0.f);
            int bin = (int)(d * 4.0f);
            if (bin > HBINS - 1) bin = HBINS - 1;
            atomicAdd(&hloc[bin], 1u);
        }
    __syncthreads();
    for (int i = t; i < HBINS; i += 256) {
        unsigned int v = hloc[i];
        if (v) atomicAdd(&hist[i], v);
    }
}

__global__ __launch_bounds__(256, 1) void k_median(
    const unsigned int* __restrict__ hist, float* __restrict__ params) {
    __shared__ unsigned int hsum[HBINS];
    __shared__ unsigned int part[256];
    __shared__ float vv[2];
    int t = threadIdx.x;
    for (int i = t; i < HBINS / 4; i += 256)
        ((uint4*)hsum)[i] = ((const uint4*)hist)[i];
    __syncthreads();
    median_from_lds(hsum, part, vv, t);
    if (t == 0) {
        float med = 0.5f * (vv[0] + vv[1]);
        float bw = fminf(fmaxf(sqrtf(med * 0.5f), 0.1f), 10.0f);
        float h2 = bw * bw;
        params[0] = 1.0f / (2.0f * h2);
        params[1] = 1.0f / h2;
        params[2] = 1.0f / (h2 * h2);
        params[3] = (float)DIM / h2;
    }
}

static __device__ __forceinline__ void store_hi(unsigned short* tile, int r, int k0,
                                                float4 v0, float4 v1) {
    bf16x8 h;
    h[0] = (short)f2bf_rne(v0.x); h[1] = (short)f2bf_rne(v0.y);
    h[2] = (short)f2bf_rne(v0.z); h[3] = (short)f2bf_rne(v0.w);
    h[4] = (short)f2bf_rne(v1.x); h[5] = (short)f2bf_rne(v1.y);
    h[6] = (short)f2bf_rne(v1.z); h[7] = (short)f2bf_rne(v1.w);
    *(bf16x8*)&tile[swz(r, k0)] = h;
}
static __device__ __forceinline__ void store_hilo(unsigned short* th, unsigned short* tl,
                                                  int r, int k0, float4 v0, float4 v1) {
    float f[8] = {v0.x, v0.y, v0.z, v0.w, v1.x, v1.y, v1.z, v1.w};
    bf16x8 h, l;
#pragma unroll
    for (int j = 0; j < 8; ++j) {
        unsigned short hh = f2bf_rne(f[j]);
        h[j] = (short)hh;
        l[j] = (short)f2bf_rne(f[j] - bf2f(hh));
    }
    *(bf16x8*)&th[swz(r, k0)] = h;
    *(bf16x8*)&tl[swz(r, k0)] = l;
}

__global__ __launch_bounds__(256, 2) void k_main_fb(
    const float* __restrict__ X, const float* __restrict__ SX,
    const float* __restrict__ Y, const float* __restrict__ SY,
    const float* __restrict__ x2g, const float* __restrict__ y2g,
    const float* __restrict__ ysyg, const float* __restrict__ params,
    float* __restrict__ out) {
    __shared__ __align__(16) unsigned short tX[4096];
    __shared__ __align__(16) unsigned short tSXH[4096];
    __shared__ __align__(16) unsigned short tSXL[4096];
    __shared__ __align__(16) unsigned short tY[2048];
    __shared__ __align__(16) unsigned short tSYH[2048];
    __shared__ __align__(16) unsigned short tSYL[2048];
    __shared__ float x2s[128];
    __shared__ float y2s[64];
    __shared__ float ysys[64];

    int t = threadIdx.x;
    int bm = blockIdx.y, bn = blockIdx.x;
    if (t < 128) x2s[t] = x2g[bm * 128 + t];
    else if (t < 192) y2s[t - 128] = y2g[bn * 64 + (t - 128)];
    else ysys[t - 192] = ysyg[bn * 64 + (t - 192)];

    int lane = t & 63, w = t >> 6, wm = w >> 1, wn = w & 1;
    f32x4 axy[4][2], ass[4][2], axsy[4][2];
#pragma unroll
    for (int i = 0; i < 4; ++i)
#pragma unroll
        for (int j = 0; j < 2; ++j) {
            axy[i][j] = (f32x4)0.f; ass[i][j] = (f32x4)0.f; axsy[i][j] = (f32x4)0.f;
        }

    for (int kt = 0; kt < DIM / 32; ++kt) {
        int kb = kt * 32;
#pragma unroll
        for (int h = 0; h < 2; ++h) {
            int s = t + h * 256;
            int r = s >> 2, k0 = (s & 3) * 8;
            const float* gx = X + (size_t)(bm * 128 + r) * DIM + kb + k0;
            store_hi(tX, r, k0, *(const float4*)gx, *(const float4*)(gx + 4));
            const float* gs = SX + (size_t)(bm * 128 + r) * DIM + kb + k0;
            store_hilo(tSXH, tSXL, r, k0, *(const float4*)gs, *(const float4*)(gs + 4));
        }
        {
            int r = t >> 2, k0 = (t & 3) * 8;
            const float* gy = Y + (size_t)(bn * 64 + r) * DIM + kb + k0;
            store_hi(tY, r, k0, *(const float4*)gy, *(const float4*)(gy + 4));
            const float* gq = SY + (size_t)(bn * 64 + r) * DIM + kb + k0;
            store_hilo(tSYH, tSYL, r, k0, *(const float4*)gq, *(const float4*)(gq + 4));
        }
        __syncthreads();

        int fr = lane & 15, fk = (lane >> 4) * 8;
        bf16x8 aX[4], aSH[4], aSL[4];
#pragma unroll
        for (int fm = 0; fm < 4; ++fm) {
            int ix = swz(wm * 64 + fm * 16 + fr, fk);
            aX[fm] = *(const bf16x8*)&tX[ix];
            aSH[fm] = *(const bf16x8*)&tSXH[ix];
            aSL[fm] = *(const bf16x8*)&tSXL[ix];
        }
#pragma unroll
        for (int fn = 0; fn < 2; ++fn) {
            int iy = swz(wn * 32 + fn * 16 + fr, fk);
            bf16x8 bY = *(const bf16x8*)&tY[iy];
            bf16x8 bH = *(const bf16x8*)&tSYH[iy];
            bf16x8 bL = *(const bf16x8*)&tSYL[iy];
#pragma unroll
            for (int fm = 0; fm < 4; ++fm) {
                axy[fm][fn] = __builtin_amdgcn_mfma_f32_16x16x32_bf16(aX[fm], bY, axy[fm][fn], 0, 0, 0);
                ass[fm][fn] = __builtin_amdgcn_mfma_f32_16x16x32_bf16(aSH[fm], bH, ass[fm][fn], 0, 0, 0);
                ass[fm][fn] = __builtin_amdgcn_mfma_f32_16x16x32_bf16(aSH[fm], bL, ass[fm][fn], 0, 0, 0);
                ass[fm][fn] = __builtin_amdgcn_mfma_f32_16x16x32_bf16(aSL[fm], bH, ass[fm][fn], 0, 0, 0);
                axsy[fm][fn] = __builtin_amdgcn_mfma_f32_16x16x32_bf16(aX[fm], bH, axsy[fm][fn], 0, 0, 0);
            }
        }
        __syncthreads();
    }

    float c0 = params[0], c1 = params[1], c2 = params[2], c3 = params[3];
    int fr = lane & 15, fq = lane >> 4;
#pragma unroll
    for (int fm = 0; fm < 4; ++fm)
#pragma unroll
        for (int fn = 0; fn < 2; ++fn)
#pragma unroll
            for (int r = 0; r < 4; ++r) {
                int rl = wm * 64 + fm * 16 + fq * 4 + r;
                int cl = wn * 32 + fn * 16 + fr;
                float d = fmaxf(x2s[rl] + y2s[cl] - 2.0f * axy[fm][fn][r], 0.0f);
                float kv = __expf(-d * c0);
                out[(size_t)(bm * 128 + rl) * B_N + (bn * 64 + cl)] =
                    kv * ass[fm][fn][r] + (axsy[fm][fn][r] - ysys[cl]) * (kv * c1)
                    + d * kv * c2 - kv * c3;
            }
}

extern "C" void kernel_launch(void* const* d_in, const int* in_sizes, int n_in,
                              void* d_out, int out_size, void* d_ws, size_t ws_size,
                              hipStream_t stream) {
    const float* x  = (const float*)d_in[0];
    const float* sx = (const float*)d_in[1];
    const float* y  = (const float*)d_in[2];
    const float* sy = (const float*)d_in[3];
    float* out = (float*)d_out;
    char* ws = (char*)d_ws;
    float* params = (float*)(ws + OFF_PARAMS);
    float* x2 = (float*)(ws + OFF_X2);
    float* y2 = (float*)(ws + OFF_Y2);
    float* ysy = (float*)(ws + OFF_YSY);
    unsigned int* hist = (unsigned int*)(ws + OFF_HIST);
    unsigned short* tiles = (unsigned short*)(ws + OFF_TILES);

    if (ws_size >= WS_NEED) {
        // zero stats (atomic-accumulated) + hist in one contiguous memset
        hipMemsetAsync(ws + OFF_X2, 0, 3 * 16384 + HBINS * 4, stream);
        k_preAll<<<576, 256, 0, stream>>>(x, y, sy, tiles, x2, y2, ysy, hist);
        k_preC<<<dim3(32, 8), 256, 0, stream>>>(x, sx, hist, params, tiles);
        k_main<<<dim3(64, 32), dim3(256), 0, stream>>>(tiles, x2, y2, ysy, params, out);
    } else {
        hipMemsetAsync(hist, 0, HBINS * 4, stream);
        k_rowstats<<<B_N / 4, 256, 0, stream>>>(x, y, sy, x2, y2, ysy);
        k_hist_fp32<<<dim3(16, 16), dim3(256), 0, stream>>>(x, y, x2, y2, hist);
        k_median<<<1, 256, 0, stream>>>(hist, params);
        k_main_fb<<<dim3(64, 32), dim3(256), 0, stream>>>(x, sx, y, sy, x2, y2, ysy, params, out);
    }
}

// Round 19
// 81.321 us; speedup vs baseline: 1.0681x; 1.0681x over previous
//
#include <hip/hip_runtime.h>
#include <hip/hip_bf16.h>

typedef __attribute__((ext_vector_type(8))) short bf16x8;
typedef __attribute__((ext_vector_type(4))) float f32x4;

#define B_N 4096
#define DIM 512
#define HBINS 8192

// workspace byte offsets
#define OFF_PARAMS 0                 // 256 B
#define OFF_X2     256
#define OFF_Y2     16640
#define OFF_YSY    33024             // stats contiguous: [256, 49408)
#define OFF_HIST   49408             // 32 KB; [49408, 82176)
#define OFF_TILES  98304             // 4KB aligned
#define MAT_ELEMS  2097152           // 4096*512 bf16 elems per matrix (4 MB)
#define WS_NEED    (OFF_TILES + (size_t)4 * MAT_ELEMS * 2)

static __device__ __forceinline__ unsigned short f2bf_rne(float f) {
    unsigned int u = __float_as_uint(f);
    u += 0x7FFFu + ((u >> 16) & 1u);
    return (unsigned short)(u >> 16);
}
static __device__ __forceinline__ float bf2f(unsigned short h) {
    return __uint_as_float(((unsigned int)h) << 16);
}

// swizzled tile index (hist staging + fallback path)
static __device__ __forceinline__ int swz(int r, int k) {
    return r * 32 + ((((k >> 3) ^ ((r >> 1) & 3))) << 3) + (k & 7);
}

// median selection from an LDS-resident histogram (256 threads). Returns via vv[2].
static __device__ __forceinline__ void median_from_lds(
    unsigned int* hsum, unsigned int* part, float* vv, int t) {
    unsigned int s = 0;
#pragma unroll 8
    for (int b = t * 32; b < t * 32 + 32; ++b) s += hsum[b];
    part[t] = s;
    __syncthreads();
    unsigned int pre = 0;
    for (int i = 0; i < 256; ++i) {
        unsigned int v = part[i];
        if (i < t) pre += v;
    }
    const unsigned int kk1 = 131072u, kk2 = 131073u;
    unsigned int hi = pre + s;
#pragma unroll
    for (int sel = 0; sel < 2; ++sel) {
        unsigned int kk = sel ? kk2 : kk1;
        if (kk > pre && kk <= hi) {      // exactly one owner thread
            unsigned int cc = pre;
            for (int b = 0; b < 32; ++b) {
                cc += hsum[t * 32 + b];
                if (cc >= kk) { vv[sel] = ((float)(t * 32 + b) + 0.5f) * 0.25f; break; }
            }
        }
    }
    __syncthreads();
}

// FRAG-MAJOR tile layout (main path, all 4 matrices):
//   elem (row, k) of a 128x32 tile -> (row>>4)*512 + (((k>>3)&3)*16 + (row&15))*8 + (k&7)

// ---------------- K_preAll: fused conversion (c1-independent) + sample hist ----------------
// blocks 0..255  : side 0 -> mat0 = bf16(X), stats x2
// blocks 256..511: side 1 -> mat2 = bf16(Y), mat3 = bf16(SY), stats y2/ysy
// blocks 512..575: 64 sample-hist blocks (64x64 tile, full K, MFMA) -> global hist
// NO device fences / cross-block sync (r14 lesson: XCD-coherence stall).
__global__ __launch_bounds__(256) void k_preAll(
    const float* __restrict__ X, const float* __restrict__ Y,
    const float* __restrict__ SY, unsigned short* __restrict__ tiles,
    float* __restrict__ x2, float* __restrict__ y2, float* __restrict__ ysy,
    unsigned int* __restrict__ hist) {
    __shared__ __align__(16) unsigned short sAB[4096];   // hist: sA=[0,2048), sB=[2048,4096)
    __shared__ unsigned int hloc[HBINS];
    __shared__ float rn[128];

    int b = blockIdx.x, t = threadIdx.x;

    if (b < 512) {
        // -------- conversion --------
        int side = b >> 8;                 // 0: X, 1: Y/SY
        int tile = (b & 255) >> 3;
        int ky = b & 7;
        unsigned short* base0 = tiles + (size_t)side * 2 * MAT_ELEMS;
        unsigned short* base1 = base0 + MAT_ELEMS;       // side1 only (SY)
#pragma unroll
        for (int kt2 = 0; kt2 < 2; ++kt2) {
            int kt = ky * 2 + kt2;
            unsigned short* d0 = base0 + (size_t)(tile * 16 + kt) * 4096;
            unsigned short* d1 = base1 + (size_t)(tile * 16 + kt) * 4096;
#pragma unroll
            for (int c = 0; c < 2; ++c) {
                int v = c * 256 + t;
                int r = (v >> 6) * 16 + (v & 15);
                int k = ((v >> 4) & 3) << 3;
                const float* gp = (side ? Y : X) + (size_t)(tile * 128 + r) * DIM + kt * 32 + k;
                float4 p0 = *(const float4*)gp;
                float4 p1 = *(const float4*)(gp + 4);
                float pv[8] = {p0.x, p0.y, p0.z, p0.w, p1.x, p1.y, p1.z, p1.w};
                float s1 = 0.f, s2 = 0.f;
                bf16x8 h0;
                if (side) {
                    const float* gq = SY + (size_t)(tile * 128 + r) * DIM + kt * 32 + k;
                    float4 q0 = *(const float4*)gq;
                    float4 q1 = *(const float4*)(gq + 4);
                    float qv[8] = {q0.x, q0.y, q0.z, q0.w, q1.x, q1.y, q1.z, q1.w};
                    bf16x8 h1;
#pragma unroll
                    for (int j = 0; j < 8; ++j) {
                        s1 += pv[j] * pv[j];
                        s2 += pv[j] * qv[j];
                        h0[j] = (short)f2bf_rne(pv[j]);
                        h1[j] = (short)f2bf_rne(qv[j]);
                    }
                    *(bf16x8*)&d1[v * 8] = h1;
                } else {
#pragma unroll
                    for (int j = 0; j < 8; ++j) {
                        s1 += pv[j] * pv[j];
                        h0[j] = (short)f2bf_rne(pv[j]);
                    }
                }
                *(bf16x8*)&d0[v * 8] = h0;
                s1 += __shfl_xor(s1, 16); s1 += __shfl_xor(s1, 32);
                if (side) { s2 += __shfl_xor(s2, 16); s2 += __shfl_xor(s2, 32); }
                if ((t & 48) == 0) {
                    int row = tile * 128 + r;
                    if (side == 0) {
                        atomicAdd(&x2[row], s1);
                    } else {
                        atomicAdd(&y2[row], s1);
                        atomicAdd(&ysy[row], s2);
                    }
                }
            }
        }
    } else {
        // -------- sample histogram (64x64 tile, full K) --------
        unsigned short* sA = &sAB[0];
        unsigned short* sB = &sAB[2048];
        float* x2s = &rn[0];
        float* y2s = &rn[64];
        int hb = b - 512;
        int bi = hb >> 3, bj = hb & 7;
        for (int i = t; i < HBINS; i += 256) hloc[i] = 0;

        int lane = t & 63, w = t >> 6;
        int wm = w >> 1, wn = w & 1;
        int fr = lane & 15, fko = (lane >> 4) * 8;

        f32x4 axy[2][2];
#pragma unroll
        for (int i = 0; i < 2; ++i)
#pragma unroll
            for (int j = 0; j < 2; ++j) axy[i][j] = (f32x4)0.f;

        int r = t >> 2, k0 = (t & 3) * 8;
        const float* gx = X + (size_t)(bi * 64 + r) * DIM + k0;
        const float* gy = Y + (size_t)(bj * 64 + r) * DIM + k0;

        int ixA[2], ixB[2];
#pragma unroll
        for (int fm = 0; fm < 2; ++fm) ixA[fm] = swz(wm * 32 + fm * 16 + fr, fko);
#pragma unroll
        for (int fn = 0; fn < 2; ++fn) ixB[fn] = swz(wn * 32 + fn * 16 + fr, fko);

        float na = 0.f, nb = 0.f;
        float4 A0, A1, B0, B1;
#define LDK(kt_) do {                                                       \
            A0 = *(const float4*)(gx + (kt_) * 32);                         \
            A1 = *(const float4*)(gx + (kt_) * 32 + 4);                     \
            B0 = *(const float4*)(gy + (kt_) * 32);                         \
            B1 = *(const float4*)(gy + (kt_) * 32 + 4);                     \
        } while (0)

        LDK(0);
        for (int kt = 0; kt < 16; ++kt) {
            float av[8] = {A0.x, A0.y, A0.z, A0.w, A1.x, A1.y, A1.z, A1.w};
            float bv[8] = {B0.x, B0.y, B0.z, B0.w, B1.x, B1.y, B1.z, B1.w};
            bf16x8 ha, hb2;
#pragma unroll
            for (int j = 0; j < 8; ++j) {
                na += av[j] * av[j];
                nb += bv[j] * bv[j];
                ha[j] = (short)f2bf_rne(av[j]);
                hb2[j] = (short)f2bf_rne(bv[j]);
            }
            __syncthreads();
            *(bf16x8*)&sA[swz(r, k0)] = ha;
            *(bf16x8*)&sB[swz(r, k0)] = hb2;
            if (kt < 15) LDK(kt + 1);
            __syncthreads();

            bf16x8 aX[2];
#pragma unroll
            for (int fm = 0; fm < 2; ++fm) aX[fm] = *(const bf16x8*)&sA[ixA[fm]];
#pragma unroll
            for (int fn = 0; fn < 2; ++fn) {
                bf16x8 bY = *(const bf16x8*)&sB[ixB[fn]];
#pragma unroll
                for (int fm = 0; fm < 2; ++fm)
                    axy[fm][fn] = __builtin_amdgcn_mfma_f32_16x16x32_bf16(aX[fm], bY, axy[fm][fn], 0, 0, 0);
            }
        }
#undef LDK

        na += __shfl_xor(na, 1); na += __shfl_xor(na, 2);
        nb += __shfl_xor(nb, 1); nb += __shfl_xor(nb, 2);
        if ((t & 3) == 0) { x2s[r] = na; y2s[r] = nb; }
        __syncthreads();

        int fq = lane >> 4;
#pragma unroll
        for (int fm = 0; fm < 2; ++fm)
#pragma unroll
            for (int fn = 0; fn < 2; ++fn)
#pragma unroll
                for (int rr = 0; rr < 4; ++rr) {
                    int rl = wm * 32 + fm * 16 + fq * 4 + rr;
                    int cl = wn * 32 + fn * 16 + fr;
                    float d = fmaxf(x2s[rl] + y2s[cl] - 2.0f * axy[fm][fn][rr], 0.0f);
                    int bin = (int)(d * 4.0f);
                    if (bin > HBINS - 1) bin = HBINS - 1;
                    atomicAdd(&hloc[bin], 1u);
                }
        __syncthreads();
        for (int i = t; i < HBINS; i += 256) {
            unsigned int v = hloc[i];
            if (v) atomicAdd(&hist[i], v);
        }
    }
}

// ---------------- K_preC: per-block median + mat1 = bf16(SX + c1*X) ----------------
__global__ __launch_bounds__(256) void k_preC(
    const float* __restrict__ X, const float* __restrict__ SX,
    const unsigned int* __restrict__ hist, float* __restrict__ params,
    unsigned short* __restrict__ tiles) {
    __shared__ unsigned int hsum[HBINS];
    __shared__ unsigned int part[256];
    __shared__ float vv[2];
    int t = threadIdx.x;
    for (int i = t; i < HBINS / 4; i += 256)
        ((uint4*)hsum)[i] = ((const uint4*)hist)[i];
    __syncthreads();
    median_from_lds(hsum, part, vv, t);
    float med = 0.5f * (vv[0] + vv[1]);
    float bw = fminf(fmaxf(sqrtf(med * 0.5f), 0.1f), 10.0f);
    float h2 = bw * bw;
    float c1 = 1.0f / h2;
    if (blockIdx.x == 0 && blockIdx.y == 0 && t == 0) {
        params[0] = 1.0f / (2.0f * h2);
        params[1] = c1;
        params[2] = 1.0f / (h2 * h2);
        params[3] = (float)DIM / h2;
    }

    int tile = blockIdx.x;
    unsigned short* base1 = tiles + MAT_ELEMS;
#pragma unroll
    for (int kt2 = 0; kt2 < 2; ++kt2) {
        int kt = blockIdx.y * 2 + kt2;
        unsigned short* d1 = base1 + (size_t)(tile * 16 + kt) * 4096;
#pragma unroll
        for (int c = 0; c < 2; ++c) {
            int v = c * 256 + t;
            int r = (v >> 6) * 16 + (v & 15);
            int k = ((v >> 4) & 3) << 3;
            const float* gp = X + (size_t)(tile * 128 + r) * DIM + kt * 32 + k;
            const float* gq = SX + (size_t)(tile * 128 + r) * DIM + kt * 32 + k;
            float4 p0 = *(const float4*)gp;
            float4 p1 = *(const float4*)(gp + 4);
            float4 q0 = *(const float4*)gq;
            float4 q1 = *(const float4*)(gq + 4);
            float pv[8] = {p0.x, p0.y, p0.z, p0.w, p1.x, p1.y, p1.z, p1.w};
            float qv[8] = {q0.x, q0.y, q0.z, q0.w, q1.x, q1.y, q1.z, q1.w};
            bf16x8 h1;
#pragma unroll
            for (int j = 0; j < 8; ++j) h1[j] = (short)f2bf_rne(qv[j] + c1 * pv[j]);
            *(bf16x8*)&d1[v * 8] = h1;
        }
    }
}

// ---------------- K_main: exact r13 structure (best measured: ~50.7 us) ----------------
#define GLD(g, l) __builtin_amdgcn_global_load_lds(                                   \
    (const __attribute__((address_space(1))) void*)(g),                               \
    (__attribute__((address_space(3))) void*)(l), 16, 0, 0)

__global__ __launch_bounds__(256, 2) void k_main(
    const unsigned short* __restrict__ tiles,
    const float* __restrict__ x2g, const float* __restrict__ y2g,
    const float* __restrict__ ysyg, const float* __restrict__ params,
    float* __restrict__ out) {
    __shared__ __align__(16) unsigned short sA[2][4096];  // X, frag-major 128x32 tiles
    __shared__ __align__(16) unsigned short sB[2][4096];  // Y
    __shared__ float x2s[128], y2s[128], ysys[128];

    int t = threadIdx.x;
    int bm = blockIdx.y, bn = blockIdx.x;
    if (t < 128) x2s[t] = x2g[bm * 128 + t];
    else { y2s[t - 128] = y2g[bn * 128 + (t - 128)]; ysys[t - 128] = ysyg[bn * 128 + (t - 128)]; }
    __syncthreads();

    int lane = t & 63, w = t >> 6;
    int wm = w >> 1, wn = w & 1;       // wave tile 64x64 at (wm*64, wn*64)

    f32x4 axy[4][4], acb[4][4];
#pragma unroll
    for (int i = 0; i < 4; ++i)
#pragma unroll
        for (int j = 0; j < 4; ++j) { axy[i][j] = (f32x4)0.f; acb[i][j] = (f32x4)0.f; }

    const unsigned short* gaX = tiles + (size_t)(bm * 16) * 4096 + t * 8;
    const unsigned short* gbY = tiles + (size_t)2 * MAT_ELEMS + (size_t)(bn * 16) * 4096 + t * 8;
    const unsigned short* gaC = tiles + (size_t)MAT_ELEMS + (size_t)(bm * 16) * 4096
                              + (wm * 4) * 512 + lane * 8;
    const unsigned short* gbS = tiles + (size_t)3 * MAT_ELEMS + (size_t)(bn * 16) * 4096
                              + (wn * 4) * 512 + lane * 8;

#define STAGE(buf, kt_) do {                                                     \
        const unsigned short* pa_ = gaX + (size_t)(kt_) * 4096;                  \
        const unsigned short* pb_ = gbY + (size_t)(kt_) * 4096;                  \
        GLD(pa_,        &sA[buf][t * 8]);                                        \
        GLD(pa_ + 2048, &sA[buf][2048 + t * 8]);                                 \
        GLD(pb_,        &sB[buf][t * 8]);                                        \
        GLD(pb_ + 2048, &sB[buf][2048 + t * 8]);                                 \
    } while (0)

#define FRAGLD(dC, dS, kt_) do {                                                 \
        const unsigned short* pc_ = gaC + (size_t)(kt_) * 4096;                  \
        const unsigned short* ps_ = gbS + (size_t)(kt_) * 4096;                  \
        dC[0] = *(const bf16x8*)(pc_);        dS[0] = *(const bf16x8*)(ps_);     \
        dC[1] = *(const bf16x8*)(pc_ + 512);  dS[1] = *(const bf16x8*)(ps_ + 512);\
        dC[2] = *(const bf16x8*)(pc_ + 1024); dS[2] = *(const bf16x8*)(ps_ + 1024);\
        dC[3] = *(const bf16x8*)(pc_ + 1536); dS[3] = *(const bf16x8*)(ps_ + 1536);\
    } while (0)

    int ixA[4], ixB[4];
#pragma unroll
    for (int fm = 0; fm < 4; ++fm) ixA[fm] = (wm * 4 + fm) * 512 + lane * 8;
#pragma unroll
    for (int fn = 0; fn < 4; ++fn) ixB[fn] = (wn * 4 + fn) * 512 + lane * 8;

    bf16x8 fC0[4], fS0[4], fC1[4], fS1[4];

#define KSTEP(CB, CURC, CURS, NXTC, NXTS, NKT, DOPF) do {                        \
        asm volatile("s_waitcnt vmcnt(8)" ::: "memory");   /* staging of CB done */\
        __builtin_amdgcn_sched_barrier(0);                                       \
        __builtin_amdgcn_s_barrier();                                            \
        __builtin_amdgcn_sched_barrier(0);                                       \
        if (DOPF) {                                                              \
            STAGE(CB ^ 1, NKT);                                                  \
            FRAGLD(NXTC, NXTS, NKT);                                             \
        }                                                                        \
        bf16x8 dX[4], dY[4];                                                     \
        dX[0] = *(const bf16x8*)&sA[CB][ixA[0]];                                 \
        dX[1] = *(const bf16x8*)&sA[CB][ixA[1]];                                 \
        dX[2] = *(const bf16x8*)&sA[CB][ixA[2]];                                 \
        dX[3] = *(const bf16x8*)&sA[CB][ixA[3]];                                 \
        dY[0] = *(const bf16x8*)&sB[CB][ixB[0]];                                 \
        dY[1] = *(const bf16x8*)&sB[CB][ixB[1]];                                 \
        dY[2] = *(const bf16x8*)&sB[CB][ixB[2]];                                 \
        dY[3] = *(const bf16x8*)&sB[CB][ixB[3]];                                 \
        __builtin_amdgcn_s_setprio(1);                                           \
        _Pragma("unroll")                                                        \
        for (int fn_ = 0; fn_ < 4; ++fn_) {                                      \
            _Pragma("unroll")                                                    \
            for (int fm_ = 0; fm_ < 4; ++fm_) {                                  \
                axy[fm_][fn_] = __builtin_amdgcn_mfma_f32_16x16x32_bf16(         \
                    dX[fm_], dY[fn_], axy[fm_][fn_], 0, 0, 0);                   \
                acb[fm_][fn_] = __builtin_amdgcn_mfma_f32_16x16x32_bf16(         \
                    CURC[fm_], CURS[fn_], acb[fm_][fn_], 0, 0, 0);               \
            }                                                                    \
        }                                                                        \
        __builtin_amdgcn_s_setprio(0);                                           \
        __builtin_amdgcn_sched_barrier(0);                                       \
    } while (0)

    STAGE(0, 0);
    FRAGLD(fC0, fS0, 0);

    for (int k2 = 0; k2 < 7; ++k2) {
        KSTEP(0, fC0, fS0, fC1, fS1, 2 * k2 + 1, 1);
        KSTEP(1, fC1, fS1, fC0, fS0, 2 * k2 + 2, 1);
    }
    KSTEP(0, fC0, fS0, fC1, fS1, 15, 1);
    KSTEP(1, fC1, fS1, fC0, fS0, 0, 0);
#undef KSTEP
#undef STAGE
#undef FRAGLD

    float c0 = params[0], c1 = params[1], c2 = params[2], c3 = params[3];
    int fr = lane & 15, fq = lane >> 4;
#pragma unroll
    for (int fm = 0; fm < 4; ++fm) {
#pragma unroll
        for (int fn = 0; fn < 4; ++fn) {
#pragma unroll
            for (int r = 0; r < 4; ++r) {
                int rl = wm * 64 + fm * 16 + fq * 4 + r;
                int cl = wn * 64 + fn * 16 + fr;
                float d = fmaxf(x2s[rl] + y2s[cl] - 2.0f * axy[fm][fn][r], 0.0f);
                float kv = __expf(-d * c0);
                out[(size_t)(bm * 128 + rl) * B_N + (bn * 128 + cl)] =
                    kv * (acb[fm][fn][r] - c1 * ysys[cl] + d * c2 - c3);
            }
        }
    }
}

// ---------------- Fallback path (small ws) ----------------
__global__ void k_rowstats(const float* __restrict__ X, const float* __restrict__ Y,
                           const float* __restrict__ SY,
                           float* __restrict__ x2, float* __restrict__ y2,
                           float* __restrict__ ysy) {
    int t = threadIdx.x;
    int r = blockIdx.x * 4 + (t >> 6);
    int lane = t & 63;
    const float4* px = (const float4*)(X + (size_t)r * DIM) + lane * 2;
    const float4* py = (const float4*)(Y + (size_t)r * DIM) + lane * 2;
    const float4* ps = (const float4*)(SY + (size_t)r * DIM) + lane * 2;
    float4 a0 = px[0], a1 = px[1];
    float4 b0 = py[0], b1 = py[1];
    float4 c0 = ps[0], c1 = ps[1];
    float s1 = a0.x*a0.x + a0.y*a0.y + a0.z*a0.z + a0.w*a0.w
             + a1.x*a1.x + a1.y*a1.y + a1.z*a1.z + a1.w*a1.w;
    float s2 = b0.x*b0.x + b0.y*b0.y + b0.z*b0.z + b0.w*b0.w
             + b1.x*b1.x + b1.y*b1.y + b1.z*b1.z + b1.w*b1.w;
    float s3 = b0.x*c0.x + b0.y*c0.y + b0.z*c0.z + b0.w*c0.w
             + b1.x*c1.x + b1.y*c1.y + b1.z*c1.z + b1.w*c1.w;
#pragma unroll
    for (int o = 32; o > 0; o >>= 1) {
        s1 += __shfl_down(s1, o);
        s2 += __shfl_down(s2, o);
        s3 += __shfl_down(s3, o);
    }
    if (lane == 0) { x2[r] = s1; y2[r] = s2; ysy[r] = s3; }
}

__global__ void k_hist_fp32(const float* __restrict__ X, const float* __restrict__ Y,
                            const float* __restrict__ x2, const float* __restrict__ y2,
                            unsigned int* __restrict__ hist) {
    __shared__ float xs[32][68];
    __shared__ float ys[32][68];
    __shared__ unsigned int hloc[HBINS];
    int t = threadIdx.x;
    for (int i = t; i < HBINS; i += 256) hloc[i] = 0;
    int i0 = blockIdx.y * 32, j0 = blockIdx.x * 32;
    float a00 = 0.f, a01 = 0.f, a10 = 0.f, a11 = 0.f;
    int ti = (t >> 4) * 2, tj = (t & 15) * 2;
    for (int c = 0; c < 8; ++c) {
        __syncthreads();
        int rr = t >> 3, cc = (t & 7) * 8;
        const float* gx = X + (size_t)(i0 + rr) * DIM + c * 64 + cc;
        *(float4*)&xs[rr][cc] = *(const float4*)gx;
        *(float4*)&xs[rr][cc + 4] = *(const float4*)(gx + 4);
        const float* gy = Y + (size_t)(j0 + rr) * DIM + c * 64 + cc;
        *(float4*)&ys[rr][cc] = *(const float4*)gy;
        *(float4*)&ys[rr][cc + 4] = *(const float4*)(gy + 4);
        __syncthreads();
        for (int kk = 0; kk < 64; ++kk) {
            float a0 = xs[ti][kk], a1 = xs[ti + 1][kk];
            float b0 = ys[tj][kk], b1 = ys[tj + 1][kk];
            a00 += a0 * b0; a01 += a0 * b1; a10 += a1 * b0; a11 += a1 * b1;
        }
    }
    float s[2][2] = {{a00, a01}, {a10, a11}};
#pragma unroll
    for (int ii = 0; ii < 2; ++ii)
#pragma unroll
        for (int jj = 0; jj < 2; ++jj) {
            float d = fmaxf(x2[i0 + ti + ii] + y2[j0 + tj + jj] - 2.f * s[ii][jj], 0.f);
            int bin = (int)(d * 4.0f);
            if (bin > HBINS - 1) bin = HBINS - 1;
            atomicAdd(&hloc[bin], 1u);
        }
    __syncthreads();
    for (int i = t; i < HBINS; i += 256) {
        unsigned int v = hloc[i];
        if (v) atomicAdd(&hist[i], v);
    }
}

__global__ __launch_bounds__(256, 1) void k_median(
    const unsigned int* __restrict__ hist, float* __restrict__ params) {
    __shared__ unsigned int hsum[HBINS];
    __shared__ unsigned int part[256];
    __shared__ float vv[2];
    int t = threadIdx.x;
    for (int i = t; i < HBINS / 4; i += 256)
        ((uint4*)hsum)[i] = ((const uint4*)hist)[i];
    __syncthreads();
    median_from_lds(hsum, part, vv, t);
    if (t == 0) {
        float med = 0.5f * (vv[0] + vv[1]);
        float bw = fminf(fmaxf(sqrtf(med * 0.5f), 0.1f), 10.0f);
        float h2 = bw * bw;
        params[0] = 1.0f / (2.0f * h2);
        params[1] = 1.0f / h2;
        params[2] = 1.0f / (h2 * h2);
        params[3] = (float)DIM / h2;
    }
}

static __device__ __forceinline__ void store_hi(unsigned short* tile, int r, int k0,
                                                float4 v0, float4 v1) {
    bf16x8 h;
    h[0] = (short)f2bf_rne(v0.x); h[1] = (short)f2bf_rne(v0.y);
    h[2] = (short)f2bf_rne(v0.z); h[3] = (short)f2bf_rne(v0.w);
    h[4] = (short)f2bf_rne(v1.x); h[5] = (short)f2bf_rne(v1.y);
    h[6] = (short)f2bf_rne(v1.z); h[7] = (short)f2bf_rne(v1.w);
    *(bf16x8*)&tile[swz(r, k0)] = h;
}
static __device__ __forceinline__ void store_hilo(unsigned short* th, unsigned short* tl,
                                                  int r, int k0, float4 v0, float4 v1) {
    float f[8] = {v0.x, v0.y, v0.z, v0.w, v1.x, v1.y, v1.z, v1.w};
    bf16x8 h, l;
#pragma unroll
    for (int j = 0; j < 8; ++j) {
        unsigned short hh = f2bf_rne(f[j]);
        h[j] = (short)hh;
        l[j] = (short)f2bf_rne(f[j] - bf2f(hh));
    }
    *(bf16x8*)&th[swz(r, k0)] = h;
    *(bf16x8*)&tl[swz(r, k0)] = l;
}

__global__ __launch_bounds__(256, 2) void k_main_fb(
    const float* __restrict__ X, const float* __restrict__ SX,
    const float* __restrict__ Y, const float* __restrict__ SY,
    const float* __restrict__ x2g, const float* __restrict__ y2g,
    const float* __restrict__ ysyg, const float* __restrict__ params,
    float* __restrict__ out) {
    __shared__ __align__(16) unsigned short tX[4096];
    __shared__ __align__(16) unsigned short tSXH[4096];
    __shared__ __align__(16) unsigned short tSXL[4096];
    __shared__ __align__(16) unsigned short tY[2048];
    __shared__ __align__(16) unsigned short tSYH[2048];
    __shared__ __align__(16) unsigned short tSYL[2048];
    __shared__ float x2s[128];
    __shared__ float y2s[64];
    __shared__ float ysys[64];

    int t = threadIdx.x;
    int bm = blockIdx.y, bn = blockIdx.x;
    if (t < 128) x2s[t] = x2g[bm * 128 + t];
    else if (t < 192) y2s[t - 128] = y2g[bn * 64 + (t - 128)];
    else ysys[t - 192] = ysyg[bn * 64 + (t - 192)];

    int lane = t & 63, w = t >> 6, wm = w >> 1, wn = w & 1;
    f32x4 axy[4][2], ass[4][2], axsy[4][2];
#pragma unroll
    for (int i = 0; i < 4; ++i)
#pragma unroll
        for (int j = 0; j < 2; ++j) {
            axy[i][j] = (f32x4)0.f; ass[i][j] = (f32x4)0.f; axsy[i][j] = (f32x4)0.f;
        }

    for (int kt = 0; kt < DIM / 32; ++kt) {
        int kb = kt * 32;
#pragma unroll
        for (int h = 0; h < 2; ++h) {
            int s = t + h * 256;
            int r = s >> 2, k0 = (s & 3) * 8;
            const float* gx = X + (size_t)(bm * 128 + r) * DIM + kb + k0;
            store_hi(tX, r, k0, *(const float4*)gx, *(const float4*)(gx + 4));
            const float* gs = SX + (size_t)(bm * 128 + r) * DIM + kb + k0;
            store_hilo(tSXH, tSXL, r, k0, *(const float4*)gs, *(const float4*)(gs + 4));
        }
        {
            int r = t >> 2, k0 = (t & 3) * 8;
            const float* gy = Y + (size_t)(bn * 64 + r) * DIM + kb + k0;
            store_hi(tY, r, k0, *(const float4*)gy, *(const float4*)(gy + 4));
            const float* gq = SY + (size_t)(bn * 64 + r) * DIM + kb + k0;
            store_hilo(tSYH, tSYL, r, k0, *(const float4*)gq, *(const float4*)(gq + 4));
        }
        __syncthreads();

        int fr = lane & 15, fk = (lane >> 4) * 8;
        bf16x8 aX[4], aSH[4], aSL[4];
#pragma unroll
        for (int fm = 0; fm < 4; ++fm) {
            int ix = swz(wm * 64 + fm * 16 + fr, fk);
            aX[fm] = *(const bf16x8*)&tX[ix];
            aSH[fm] = *(const bf16x8*)&tSXH[ix];
            aSL[fm] = *(const bf16x8*)&tSXL[ix];
        }
#pragma unroll
        for (int fn = 0; fn < 2; ++fn) {
            int iy = swz(wn * 32 + fn * 16 + fr, fk);
            bf16x8 bY = *(const bf16x8*)&tY[iy];
            bf16x8 bH = *(const bf16x8*)&tSYH[iy];
            bf16x8 bL = *(const bf16x8*)&tSYL[iy];
#pragma unroll
            for (int fm = 0; fm < 4; ++fm) {
                axy[fm][fn] = __builtin_amdgcn_mfma_f32_16x16x32_bf16(aX[fm], bY, axy[fm][fn], 0, 0, 0);
                ass[fm][fn] = __builtin_amdgcn_mfma_f32_16x16x32_bf16(aSH[fm], bH, ass[fm][fn], 0, 0, 0);
                ass[fm][fn] = __builtin_amdgcn_mfma_f32_16x16x32_bf16(aSH[fm], bL, ass[fm][fn], 0, 0, 0);
                ass[fm][fn] = __builtin_amdgcn_mfma_f32_16x16x32_bf16(aSL[fm], bH, ass[fm][fn], 0, 0, 0);
                axsy[fm][fn] = __builtin_amdgcn_mfma_f32_16x16x32_bf16(aX[fm], bH, axsy[fm][fn], 0, 0, 0);
            }
        }
        __syncthreads();
    }

    float c0 = params[0], c1 = params[1], c2 = params[2], c3 = params[3];
    int fr = lane & 15, fq = lane >> 4;
#pragma unroll
    for (int fm = 0; fm < 4; ++fm)
#pragma unroll
        for (int fn = 0; fn < 2; ++fn)
#pragma unroll
            for (int r = 0; r < 4; ++r) {
                int rl = wm * 64 + fm * 16 + fq * 4 + r;
                int cl = wn * 32 + fn * 16 + fr;
                float d = fmaxf(x2s[rl] + y2s[cl] - 2.0f * axy[fm][fn][r], 0.0f);
                float kv = __expf(-d * c0);
                out[(size_t)(bm * 128 + rl) * B_N + (bn * 64 + cl)] =
                    kv * ass[fm][fn][r] + (axsy[fm][fn][r] - ysys[cl]) * (kv * c1)
                    + d * kv * c2 - kv * c3;
            }
}

extern "C" void kernel_launch(void* const* d_in, const int* in_sizes, int n_in,
                              void* d_out, int out_size, void* d_ws, size_t ws_size,
                              hipStream_t stream) {
    const float* x  = (const float*)d_in[0];
    const float* sx = (const float*)d_in[1];
    const float* y  = (const float*)d_in[2];
    const float* sy = (const float*)d_in[3];
    float* out = (float*)d_out;
    char* ws = (char*)d_ws;
    float* params = (float*)(ws + OFF_PARAMS);
    float* x2 = (float*)(ws + OFF_X2);
    float* y2 = (float*)(ws + OFF_Y2);
    float* ysy = (float*)(ws + OFF_YSY);
    unsigned int* hist = (unsigned int*)(ws + OFF_HIST);
    unsigned short* tiles = (unsigned short*)(ws + OFF_TILES);

    if (ws_size >= WS_NEED) {
        // zero stats (atomic-accumulated) + hist in one contiguous memset
        hipMemsetAsync(ws + OFF_X2, 0, 3 * 16384 + HBINS * 4, stream);
        k_preAll<<<576, 256, 0, stream>>>(x, y, sy, tiles, x2, y2, ysy, hist);
        k_preC<<<dim3(32, 8), 256, 0, stream>>>(x, sx, hist, params, tiles);
        k_main<<<dim3(32, 32), dim3(256), 0, stream>>>(tiles, x2, y2, ysy, params, out);
    } else {
        hipMemsetAsync(hist, 0, HBINS * 4, stream);
        k_rowstats<<<B_N / 4, 256, 0, stream>>>(x, y, sy, x2, y2, ysy);
        k_hist_fp32<<<dim3(16, 16), dim3(256), 0, stream>>>(x, y, x2, y2, hist);
        k_median<<<1, 256, 0, stream>>>(hist, params);
        k_main_fb<<<dim3(64, 32), dim3(256), 0, stream>>>(x, sx, y, sy, x2, y2, ysy, params, out);
    }
}